// Round 6
// baseline (143.665 us; speedup 1.0000x reference)
//
#include <hip/hip_runtime.h>

#define NN   2500
#define NE   10000
#define EMBD 32
#define NH   4
#define DHD  8
#define FFD  32
#define EPSC 1e-5f

// Native clang vector: direct VGPR-tuple asm operand, supports swizzles.
typedef float vf4 __attribute__((ext_vector_type(4)));

__device__ __forceinline__ float dot4v(vf4 a, vf4 b) {
    return a.x * b.x + a.y * b.y + a.z * b.z + a.w * b.w;
}

// One FFN path, coalesced layout.
// Big loads (done by caller): U[j]/V[j] = float4 #(j*64+lane) of the 4KB
// layer-1 weight block -> lane holds rows {j*8 + (lane>>3)}, cols
// [(lane&7)*4 .. +4).  E = float4 #lane of the 1KB layer-2 block -> row
// lane>>1, cols [(lane&1)*4 .. +4).  FS/FD = feat cols [(lane&7)*4..+4).
// b1 = ub[lane>>1]+vb[lane>>1]; b2/g4/bt4 at cols [(lane&1)*4..+4).
__device__ __forceinline__ vf4 ffn_compute(
    const vf4* U, const vf4* V, vf4 E, vf4 FS, vf4 FD,
    float b1, vf4 b2, vf4 g4, vf4 bt4, int lane)
{
    // layer-1 partial dots: p_j = partial over 4 cols of row j*8+(lane>>3)
    float p0 = dot4v(U[0], FS) + dot4v(V[0], FD);
    float p1 = dot4v(U[1], FS) + dot4v(V[1], FD);
    float p2 = dot4v(U[2], FS) + dot4v(V[2], FD);
    float p3 = dot4v(U[3], FS) + dot4v(V[3], FD);
    #pragma unroll
    for (int m = 1; m <= 4; m <<= 1) {      // sum over the 8 col-groups
        p0 += __shfl_xor(p0, m); p1 += __shfl_xor(p1, m);
        p2 += __shfl_xor(p2, m); p3 += __shfl_xor(p3, m);
    }
    // p_j now = hpre[j*8 + (lane>>3)] (full pre-bias row dot)

    // redistribute: this lane needs hpre[f], f=lane>>1, held in slot f>>3
    // of any lane s with s>>3 == f&7.
    int f = lane >> 1;
    int s = ((f & 7) << 3) | (lane & 7);
    float h0 = __shfl(p0, s), h1 = __shfl(p1, s);
    float h2 = __shfl(p2, s), h3 = __shfl(p3, s);
    int j = lane >> 4;                      // = f>>3
    float hp = (j == 0) ? h0 : (j == 1) ? h1 : (j == 2) ? h2 : h3;
    float h  = fmaxf(hp + b1, 0.0f);        // bias+ReLU at consumer

    // layer 2: o[cols] = sum_f ew[f][cols] * h[f]; lanes of same parity
    // cover all 32 f-rows -> butterfly over bits 1..5
    vf4 o = E * h;
    #pragma unroll
    for (int m = 2; m <= 32; m <<= 1) {
        o.x += __shfl_xor(o.x, m); o.y += __shfl_xor(o.y, m);
        o.z += __shfl_xor(o.z, m); o.w += __shfl_xor(o.w, m);
    }
    o += b2;

    // LayerNorm over DH=8 (4 local + 4 in paired lane)
    float s1 = o.x + o.y + o.z + o.w;
    float s2 = o.x * o.x + o.y * o.y + o.z * o.z + o.w * o.w;
    s1 += __shfl_xor(s1, 1);
    s2 += __shfl_xor(s2, 1);
    float mean = s1 * 0.125f;
    float var  = s2 * 0.125f - mean * mean;
    float rs   = rsqrtf(var + EPSC);
    return (o - mean) * rs * g4 + bt4;
}

// All big loads are contiguous-per-instruction: instr j reads 1KB with lane
// stride 16B (4 lanes per 64B line) -> 16 line-requests/instr instead of 64.
__global__ __launch_bounds__(256, 3) void edge_kernel(
    const float* __restrict__ feat, const float* __restrict__ query,
    const float* __restrict__ skw, const float* __restrict__ dkw,
    const float* __restrict__ skb, const float* __restrict__ dkb,
    const float* __restrict__ ekw, const float* __restrict__ ekb,
    const float* __restrict__ svw, const float* __restrict__ dvw,
    const float* __restrict__ svb, const float* __restrict__ dvb,
    const float* __restrict__ evw, const float* __restrict__ evb,
    const float* __restrict__ kg, const float* __restrict__ kbeta,
    const float* __restrict__ vg, const float* __restrict__ vbeta,
    const int* __restrict__ src, const int* __restrict__ dst,
    float* __restrict__ s_den, float* __restrict__ ex_out,
    float* __restrict__ v_out)
{
    int gid = blockIdx.x * 256 + threadIdx.x;
    int wid = gid >> 6;                 // one wave per (edge, head)
    if (wid >= NE * NH) return;
    int lane = threadIdx.x & 63;
    int e    = wid >> 2;
    int hh   = wid & 3;
    int c    = lane & 7;                // L1 col-group
    int f    = lane >> 1;               // L2 row
    int half = lane & 1;                // output col-half
    int sn = src[e], dn = dst[e];
    size_t eh = (size_t)wid;

    // ---------- issue ALL big loads, fully coalesced ----------------------
    const vf4* ku_p = (const vf4*)(skw + eh * 1024);
    const vf4* kv_p = (const vf4*)(dkw + eh * 1024);
    const vf4* vu_p = (const vf4*)(svw + eh * 1024);
    const vf4* vv_p = (const vf4*)(dvw + eh * 1024);
    vf4 KU[4], KV[4], VU[4], VV[4];
    #pragma unroll
    for (int j = 0; j < 4; j++) KU[j] = ku_p[j * 64 + lane];
    #pragma unroll
    for (int j = 0; j < 4; j++) KV[j] = kv_p[j * 64 + lane];
    #pragma unroll
    for (int j = 0; j < 4; j++) VU[j] = vu_p[j * 64 + lane];
    #pragma unroll
    for (int j = 0; j < 4; j++) VV[j] = vv_p[j * 64 + lane];
    vf4 KE = ((const vf4*)(ekw + eh * 256))[lane];   // 1KB, one instr
    vf4 VE = ((const vf4*)(evw + eh * 256))[lane];
    vf4 FS = ((const vf4*)(feat + sn * EMBD))[c];
    vf4 FD = ((const vf4*)(feat + dn * EMBD))[c];
    vf4 q4 = ((const vf4*)(query + eh * 8))[half];

    // ---------- fence: keep every big load clustered up-front -------------
    __builtin_amdgcn_sched_barrier(0);
    asm volatile("" ::
        "v"(KU[0]), "v"(KU[1]), "v"(KU[2]), "v"(KU[3]),
        "v"(KV[0]), "v"(KV[1]), "v"(KV[2]), "v"(KV[3]),
        "v"(KE), "v"(FS), "v"(FD), "v"(q4));
    asm volatile("" ::
        "v"(VU[0]), "v"(VU[1]), "v"(VU[2]), "v"(VU[3]),
        "v"(VV[0]), "v"(VV[1]), "v"(VV[2]), "v"(VV[3]),
        "v"(VE));
    __builtin_amdgcn_sched_barrier(0);

    // ---------- small loads (biases, gamma/beta): tiny traffic ------------
    float kb1 = skb[eh * 32 + f] + dkb[eh * 32 + f];
    float vb1 = svb[eh * 32 + f] + dvb[eh * 32 + f];
    vf4 kb2 = ((const vf4*)(ekb + eh * 8))[half];
    vf4 vb2 = ((const vf4*)(evb + eh * 8))[half];
    vf4 kgam = ((const vf4*)kg)[half],   kbet = ((const vf4*)kbeta)[half];
    vf4 vgam = ((const vf4*)vg)[half],   vbet = ((const vf4*)vbeta)[half];

    // ---------- compute ----------------------------------------------------
    vf4 kn = ffn_compute(KU, KV, KE, FS, FD, kb1, kb2, kgam, kbet, lane);
    float lp = dot4v(kn, q4);
    lp += __shfl_xor(lp, 1);            // full DH=8 dot

    vf4 vn = ffn_compute(VU, VV, VE, FS, FD, vb1, vb2, vgam, vbet, lane);

    if (lane < 2)
        *(vf4*)(v_out + eh * 8 + half * 4) = vn;
    if (lane == 0) {
        float exv = expf(lp);           // no max-subtraction: identical softmax
        ex_out[eh] = exv;
        atomicAdd(s_den + dn * NH + hh, exv);
    }
}

__global__ void zero_kernel(float* __restrict__ p, int n) {
    int i = blockIdx.x * blockDim.x + threadIdx.x;
    if (i < n) p[i] = 0.0f;
}

__global__ void attn_agg_kernel(
    const int* __restrict__ dst, const float* __restrict__ ex,
    const float* __restrict__ s_den, const float* __restrict__ v,
    float* __restrict__ agg, float* __restrict__ attn_out)
{
    int tid = blockIdx.x * blockDim.x + threadIdx.x;
    if (tid >= NE * NH * DHD) return;
    int eh = tid >> 3;
    int dd = tid & 7;
    int e  = eh >> 2;
    int h  = eh & 3;
    int dn = dst[e];
    float a = ex[eh] / s_den[dn * NH + h];
    if (dd == 0) attn_out[eh] = a;
    atomicAdd(agg + (dn * NH + h) * DHD + dd, v[tid] * a);
}

__global__ void out_ln_kernel(
    const float* __restrict__ agg, const float* __restrict__ g,
    const float* __restrict__ b, float* __restrict__ out)
{
    int tid = blockIdx.x * blockDim.x + threadIdx.x;
    if (tid >= NN * NH) return;
    vf4 a0 = *(const vf4*)(agg + tid * 8);
    vf4 a1 = *(const vf4*)(agg + tid * 8 + 4);
    float s1 = a0.x + a0.y + a0.z + a0.w + a1.x + a1.y + a1.z + a1.w;
    float s2 = a0.x * a0.x + a0.y * a0.y + a0.z * a0.z + a0.w * a0.w
             + a1.x * a1.x + a1.y * a1.y + a1.z * a1.z + a1.w * a1.w;
    float mean = s1 * 0.125f;
    float var  = s2 * 0.125f - mean * mean;
    float rs   = rsqrtf(var + EPSC);
    vf4 g0 = *(const vf4*)(g);
    vf4 g1 = *(const vf4*)(g + 4);
    vf4 b0 = *(const vf4*)(b);
    vf4 b1 = *(const vf4*)(b + 4);
    *(vf4*)(out + tid * 8)     = (a0 - mean) * rs * g0 + b0;
    *(vf4*)(out + tid * 8 + 4) = (a1 - mean) * rs * g1 + b1;
}

extern "C" void kernel_launch(void* const* d_in, const int* in_sizes, int n_in,
                              void* d_out, int out_size, void* d_ws, size_t ws_size,
                              hipStream_t stream) {
    const float* feat  = (const float*)d_in[0];
    const float* query = (const float*)d_in[1];
    const float* skw   = (const float*)d_in[2];
    const float* dkw   = (const float*)d_in[3];
    const float* skb   = (const float*)d_in[4];
    const float* dkb   = (const float*)d_in[5];
    const float* ekw   = (const float*)d_in[6];
    const float* ekb   = (const float*)d_in[7];
    const float* svw   = (const float*)d_in[8];
    const float* dvw   = (const float*)d_in[9];
    const float* svb   = (const float*)d_in[10];
    const float* dvb   = (const float*)d_in[11];
    const float* evw   = (const float*)d_in[12];
    const float* evb   = (const float*)d_in[13];
    const float* kg    = (const float*)d_in[14];
    const float* kbeta = (const float*)d_in[15];
    const float* vg    = (const float*)d_in[16];
    const float* vbeta = (const float*)d_in[17];
    const float* og    = (const float*)d_in[18];
    const float* obeta = (const float*)d_in[19];
    const int*   src   = (const int*)d_in[20];
    const int*   dst   = (const int*)d_in[21];
    // d_in[22] = i, always 0 (L=1)

    float* ws    = (float*)d_ws;
    float* s_den = ws;                 // N*H          = 10000
    float* agg   = ws + 10000;         // N*H*DH       = 80000
    float* ex    = ws + 90000;         // E*H          = 40000
    float* vbuf  = ws + 130000;        // E*H*DH       = 320000

    float* out  = (float*)d_out;       // N*EMB = 80000 floats

    zero_kernel<<<(90000 + 255) / 256, 256, 0, stream>>>(ws, 90000);

    edge_kernel<<<(NE * NH * 64) / 256, 256, 0, stream>>>(
        feat, query, skw, dkw, skb, dkb, ekw, ekb,
        svw, dvw, svb, dvb, evw, evb,
        kg, kbeta, vg, vbeta, src, dst,
        s_den, ex, vbuf);

    attn_agg_kernel<<<(NE * NH * DHD + 255) / 256, 256, 0, stream>>>(
        dst, ex, s_den, vbuf, agg, out + NN * EMBD);

    out_ln_kernel<<<(NN * NH + 255) / 256, 256, 0, stream>>>(
        agg, og, obeta, out);
}

// Round 7
// 143.459 us; speedup vs baseline: 1.0014x; 1.0014x over previous
//
#include <hip/hip_runtime.h>

#define NN   2500
#define NE   10000
#define EMBD 32
#define NH   4
#define DHD  8
#define FFD  32
#define EPSC 1e-5f

// Native clang vector type; supports swizzles.
typedef float vf4 __attribute__((ext_vector_type(4)));

__device__ __forceinline__ float dot4v(vf4 a, vf4 b) {
    return a.x * b.x + a.y * b.y + a.z * b.z + a.w * b.w;
}

// One FFN path, coalesced register layout.
// U[j]/V[j] = float4 #(j*64+lane) of the 4KB layer-1 weight block -> lane
// holds rows {j*8 + (lane>>3)}, cols [(lane&7)*4 .. +4).
// E = float4 #lane of the 1KB layer-2 block -> row lane>>1, cols
// [(lane&1)*4 .. +4).  FS/FD = feat cols [(lane&7)*4..+4).
// b1 = ub[lane>>1]+vb[lane>>1]; b2/g4/bt4 at cols [(lane&1)*4..+4).
__device__ __forceinline__ vf4 ffn_compute(
    const vf4* U, const vf4* V, vf4 E, vf4 FS, vf4 FD,
    float b1, vf4 b2, vf4 g4, vf4 bt4, int lane)
{
    // layer-1 partial dots: p_j = partial over 4 cols of row j*8+(lane>>3)
    float p0 = dot4v(U[0], FS) + dot4v(V[0], FD);
    float p1 = dot4v(U[1], FS) + dot4v(V[1], FD);
    float p2 = dot4v(U[2], FS) + dot4v(V[2], FD);
    float p3 = dot4v(U[3], FS) + dot4v(V[3], FD);
    #pragma unroll
    for (int m = 1; m <= 4; m <<= 1) {      // sum over the 8 col-groups
        p0 += __shfl_xor(p0, m); p1 += __shfl_xor(p1, m);
        p2 += __shfl_xor(p2, m); p3 += __shfl_xor(p3, m);
    }
    // p_j now = hpre[j*8 + (lane>>3)] (full pre-bias row dot)

    // redistribute: this lane needs hpre[f], f=lane>>1, held in slot f>>3
    // of any lane s with s>>3 == f&7.
    int f = lane >> 1;
    int s = ((f & 7) << 3) | (lane & 7);
    float h0 = __shfl(p0, s), h1 = __shfl(p1, s);
    float h2 = __shfl(p2, s), h3 = __shfl(p3, s);
    int j = lane >> 4;                      // = f>>3
    float hp = (j == 0) ? h0 : (j == 1) ? h1 : (j == 2) ? h2 : h3;
    float h  = fmaxf(hp + b1, 0.0f);        // bias+ReLU at consumer

    // layer 2: o[cols] = sum_f ew[f][cols] * h[f]; lanes of same parity
    // cover all 32 f-rows -> butterfly over bits 1..5
    vf4 o = E * h;
    #pragma unroll
    for (int m = 2; m <= 32; m <<= 1) {
        o.x += __shfl_xor(o.x, m); o.y += __shfl_xor(o.y, m);
        o.z += __shfl_xor(o.z, m); o.w += __shfl_xor(o.w, m);
    }
    o += b2;

    // LayerNorm over DH=8 (4 local + 4 in paired lane)
    float s1 = o.x + o.y + o.z + o.w;
    float s2 = o.x * o.x + o.y * o.y + o.z * o.z + o.w * o.w;
    s1 += __shfl_xor(s1, 1);
    s2 += __shfl_xor(s2, 1);
    float mean = s1 * 0.125f;
    float var  = s2 * 0.125f - mean * mean;
    float rs   = rsqrtf(var + EPSC);
    return (o - mean) * rs * g4 + bt4;
}

// One wave per (edge, head). All big loads contiguous-per-instruction
// (lane stride 16B). No launch bounds / fences: the memory pipeline is
// MSHR-concurrency-saturated regardless of schedule (R1-R6 evidence);
// high occupancy hides the post-load shuffle-chain tails.
__global__ void edge_kernel(
    const float* __restrict__ feat, const float* __restrict__ query,
    const float* __restrict__ skw, const float* __restrict__ dkw,
    const float* __restrict__ skb, const float* __restrict__ dkb,
    const float* __restrict__ ekw, const float* __restrict__ ekb,
    const float* __restrict__ svw, const float* __restrict__ dvw,
    const float* __restrict__ svb, const float* __restrict__ dvb,
    const float* __restrict__ evw, const float* __restrict__ evb,
    const float* __restrict__ kg, const float* __restrict__ kbeta,
    const float* __restrict__ vg, const float* __restrict__ vbeta,
    const int* __restrict__ src, const int* __restrict__ dst,
    float* __restrict__ s_den, float* __restrict__ ex_out,
    float* __restrict__ v_out)
{
    int gid = blockIdx.x * 256 + threadIdx.x;
    int wid = gid >> 6;                 // one wave per (edge, head)
    if (wid >= NE * NH) return;
    int lane = threadIdx.x & 63;
    int e    = wid >> 2;
    int hh   = wid & 3;
    int c    = lane & 7;                // L1 col-group
    int f    = lane >> 1;               // L2 row
    int half = lane & 1;                // output col-half
    int sn = src[e], dn = dst[e];
    size_t eh = (size_t)wid;

    // ---------- big loads, fully coalesced --------------------------------
    const vf4* ku_p = (const vf4*)(skw + eh * 1024);
    const vf4* kv_p = (const vf4*)(dkw + eh * 1024);
    const vf4* vu_p = (const vf4*)(svw + eh * 1024);
    const vf4* vv_p = (const vf4*)(dvw + eh * 1024);
    vf4 KU[4], KV[4], VU[4], VV[4];
    #pragma unroll
    for (int j = 0; j < 4; j++) KU[j] = ku_p[j * 64 + lane];
    #pragma unroll
    for (int j = 0; j < 4; j++) KV[j] = kv_p[j * 64 + lane];
    #pragma unroll
    for (int j = 0; j < 4; j++) VU[j] = vu_p[j * 64 + lane];
    #pragma unroll
    for (int j = 0; j < 4; j++) VV[j] = vv_p[j * 64 + lane];
    vf4 KE = ((const vf4*)(ekw + eh * 256))[lane];   // 1KB, one instr
    vf4 VE = ((const vf4*)(evw + eh * 256))[lane];
    vf4 FS = ((const vf4*)(feat + sn * EMBD))[c];
    vf4 FD = ((const vf4*)(feat + dn * EMBD))[c];
    vf4 q4 = ((const vf4*)(query + eh * 8))[half];

    // ---------- small loads (biases, gamma/beta) --------------------------
    float kb1 = skb[eh * 32 + f] + dkb[eh * 32 + f];
    float vb1 = svb[eh * 32 + f] + dvb[eh * 32 + f];
    vf4 kb2 = ((const vf4*)(ekb + eh * 8))[half];
    vf4 vb2 = ((const vf4*)(evb + eh * 8))[half];
    vf4 kgam = ((const vf4*)kg)[half],   kbet = ((const vf4*)kbeta)[half];
    vf4 vgam = ((const vf4*)vg)[half],   vbet = ((const vf4*)vbeta)[half];

    // ---------- compute ----------------------------------------------------
    vf4 kn = ffn_compute(KU, KV, KE, FS, FD, kb1, kb2, kgam, kbet, lane);
    float lp = dot4v(kn, q4);
    lp += __shfl_xor(lp, 1);            // full DH=8 dot

    vf4 vn = ffn_compute(VU, VV, VE, FS, FD, vb1, vb2, vgam, vbet, lane);

    if (lane < 2)
        *(vf4*)(v_out + eh * 8 + half * 4) = vn;
    if (lane == 0) {
        float exv = expf(lp);           // no max-subtraction: identical softmax
        ex_out[eh] = exv;
        atomicAdd(s_den + dn * NH + hh, exv);
    }
}

__global__ void zero_kernel(float* __restrict__ p, int n) {
    int i = blockIdx.x * blockDim.x + threadIdx.x;
    if (i < n) p[i] = 0.0f;
}

__global__ void attn_agg_kernel(
    const int* __restrict__ dst, const float* __restrict__ ex,
    const float* __restrict__ s_den, const float* __restrict__ v,
    float* __restrict__ agg, float* __restrict__ attn_out)
{
    int tid = blockIdx.x * blockDim.x + threadIdx.x;
    if (tid >= NE * NH * DHD) return;
    int eh = tid >> 3;
    int dd = tid & 7;
    int e  = eh >> 2;
    int h  = eh & 3;
    int dn = dst[e];
    float a = ex[eh] / s_den[dn * NH + h];
    if (dd == 0) attn_out[eh] = a;
    atomicAdd(agg + (dn * NH + h) * DHD + dd, v[tid] * a);
}

__global__ void out_ln_kernel(
    const float* __restrict__ agg, const float* __restrict__ g,
    const float* __restrict__ b, float* __restrict__ out)
{
    int tid = blockIdx.x * blockDim.x + threadIdx.x;
    if (tid >= NN * NH) return;
    vf4 a0 = *(const vf4*)(agg + tid * 8);
    vf4 a1 = *(const vf4*)(agg + tid * 8 + 4);
    float s1 = a0.x + a0.y + a0.z + a0.w + a1.x + a1.y + a1.z + a1.w;
    float s2 = a0.x * a0.x + a0.y * a0.y + a0.z * a0.z + a0.w * a0.w
             + a1.x * a1.x + a1.y * a1.y + a1.z * a1.z + a1.w * a1.w;
    float mean = s1 * 0.125f;
    float var  = s2 * 0.125f - mean * mean;
    float rs   = rsqrtf(var + EPSC);
    vf4 g0 = *(const vf4*)(g);
    vf4 g1 = *(const vf4*)(g + 4);
    vf4 b0 = *(const vf4*)(b);
    vf4 b1 = *(const vf4*)(b + 4);
    *(vf4*)(out + tid * 8)     = (a0 - mean) * rs * g0 + b0;
    *(vf4*)(out + tid * 8 + 4) = (a1 - mean) * rs * g1 + b1;
}

extern "C" void kernel_launch(void* const* d_in, const int* in_sizes, int n_in,
                              void* d_out, int out_size, void* d_ws, size_t ws_size,
                              hipStream_t stream) {
    const float* feat  = (const float*)d_in[0];
    const float* query = (const float*)d_in[1];
    const float* skw   = (const float*)d_in[2];
    const float* dkw   = (const float*)d_in[3];
    const float* skb   = (const float*)d_in[4];
    const float* dkb   = (const float*)d_in[5];
    const float* ekw   = (const float*)d_in[6];
    const float* ekb   = (const float*)d_in[7];
    const float* svw   = (const float*)d_in[8];
    const float* dvw   = (const float*)d_in[9];
    const float* svb   = (const float*)d_in[10];
    const float* dvb   = (const float*)d_in[11];
    const float* evw   = (const float*)d_in[12];
    const float* evb   = (const float*)d_in[13];
    const float* kg    = (const float*)d_in[14];
    const float* kbeta = (const float*)d_in[15];
    const float* vg    = (const float*)d_in[16];
    const float* vbeta = (const float*)d_in[17];
    const float* og    = (const float*)d_in[18];
    const float* obeta = (const float*)d_in[19];
    const int*   src   = (const int*)d_in[20];
    const int*   dst   = (const int*)d_in[21];
    // d_in[22] = i, always 0 (L=1)

    float* ws    = (float*)d_ws;
    float* s_den = ws;                 // N*H          = 10000
    float* agg   = ws + 10000;         // N*H*DH       = 80000
    float* ex    = ws + 90000;         // E*H          = 40000
    float* vbuf  = ws + 130000;        // E*H*DH       = 320000

    float* out  = (float*)d_out;       // N*EMB = 80000 floats

    zero_kernel<<<(90000 + 255) / 256, 256, 0, stream>>>(ws, 90000);

    edge_kernel<<<(NE * NH * 64) / 256, 256, 0, stream>>>(
        feat, query, skw, dkw, skb, dkb, ekw, ekb,
        svw, dvw, svb, dvb, evw, evb,
        kg, kbeta, vg, vbeta, src, dst,
        s_den, ex, vbuf);

    attn_agg_kernel<<<(NE * NH * DHD + 255) / 256, 256, 0, stream>>>(
        dst, ex, s_den, vbuf, agg, out + NN * EMBD);

    out_ln_kernel<<<(NN * NH + 255) / 256, 256, 0, stream>>>(
        agg, og, obeta, out);
}

// Round 8
// 127.211 us; speedup vs baseline: 1.1293x; 1.1277x over previous
//
#include <hip/hip_runtime.h>

#define NN   2500
#define NE   10000
#define EMBD 32
#define NH   4
#define DHD  8
#define FFD  32
#define EPSC 1e-5f

// Native clang vector type; supports swizzles.
typedef float vf4 __attribute__((ext_vector_type(4)));

__device__ __forceinline__ float dot4v(vf4 a, vf4 b) {
    return a.x * b.x + a.y * b.y + a.z * b.z + a.w * b.w;
}

// One FFN path, coalesced register layout (see R5/R6 comments).
__device__ __forceinline__ vf4 ffn_compute(
    const vf4* U, const vf4* V, vf4 E, vf4 FS, vf4 FD,
    float b1, vf4 b2, vf4 g4, vf4 bt4, int lane)
{
    float p0 = dot4v(U[0], FS) + dot4v(V[0], FD);
    float p1 = dot4v(U[1], FS) + dot4v(V[1], FD);
    float p2 = dot4v(U[2], FS) + dot4v(V[2], FD);
    float p3 = dot4v(U[3], FS) + dot4v(V[3], FD);
    #pragma unroll
    for (int m = 1; m <= 4; m <<= 1) {      // sum over the 8 col-groups
        p0 += __shfl_xor(p0, m); p1 += __shfl_xor(p1, m);
        p2 += __shfl_xor(p2, m); p3 += __shfl_xor(p3, m);
    }
    int f = lane >> 1;
    int s = ((f & 7) << 3) | (lane & 7);
    float h0 = __shfl(p0, s), h1 = __shfl(p1, s);
    float h2 = __shfl(p2, s), h3 = __shfl(p3, s);
    int j = lane >> 4;
    float hp = (j == 0) ? h0 : (j == 1) ? h1 : (j == 2) ? h2 : h3;
    float h  = fmaxf(hp + b1, 0.0f);

    vf4 o = E * h;
    #pragma unroll
    for (int m = 2; m <= 32; m <<= 1) {
        o.x += __shfl_xor(o.x, m); o.y += __shfl_xor(o.y, m);
        o.z += __shfl_xor(o.z, m); o.w += __shfl_xor(o.w, m);
    }
    o += b2;

    float s1 = o.x + o.y + o.z + o.w;
    float s2 = o.x * o.x + o.y * o.y + o.z * o.z + o.w * o.w;
    s1 += __shfl_xor(s1, 1);
    s2 += __shfl_xor(s2, 1);
    float mean = s1 * 0.125f;
    float var  = s2 * 0.125f - mean * mean;
    float rs   = rsqrtf(var + EPSC);
    return (o - mean) * rs * g4 + bt4;
}

// One wave per (edge, head). Streamed weights use nontemporal loads (the
// 762MB working set thrashes the 256MB L3 anyway - don't pollute it).
// Fused epilogue: atomicAdd of UNNORMALIZED ex*v into agg; the final
// kernel divides by the softmax denominator once per node-head.
__global__ void edge_kernel(
    const float* __restrict__ feat, const float* __restrict__ query,
    const float* __restrict__ skw, const float* __restrict__ dkw,
    const float* __restrict__ skb, const float* __restrict__ dkb,
    const float* __restrict__ ekw, const float* __restrict__ ekb,
    const float* __restrict__ svw, const float* __restrict__ dvw,
    const float* __restrict__ svb, const float* __restrict__ dvb,
    const float* __restrict__ evw, const float* __restrict__ evb,
    const float* __restrict__ kg, const float* __restrict__ kbeta,
    const float* __restrict__ vg, const float* __restrict__ vbeta,
    const int* __restrict__ src, const int* __restrict__ dst,
    float* __restrict__ s_den, float* __restrict__ agg,
    float* __restrict__ ex_out)
{
    int gid = blockIdx.x * 256 + threadIdx.x;
    int wid = gid >> 6;                 // one wave per (edge, head)
    if (wid >= NE * NH) return;
    int lane = threadIdx.x & 63;
    int e    = wid >> 2;
    int hh   = wid & 3;
    int c    = lane & 7;                // L1 col-group
    int f    = lane >> 1;               // L2 row
    int half = lane & 1;                // output col-half
    int sn = src[e], dn = dst[e];
    size_t eh = (size_t)wid;

    // ---------- big loads, coalesced + nontemporal ------------------------
    const vf4* ku_p = (const vf4*)(skw + eh * 1024);
    const vf4* kv_p = (const vf4*)(dkw + eh * 1024);
    const vf4* vu_p = (const vf4*)(svw + eh * 1024);
    const vf4* vv_p = (const vf4*)(dvw + eh * 1024);
    vf4 KU[4], KV[4], VU[4], VV[4];
    #pragma unroll
    for (int j = 0; j < 4; j++) KU[j] = __builtin_nontemporal_load(&ku_p[j * 64 + lane]);
    #pragma unroll
    for (int j = 0; j < 4; j++) KV[j] = __builtin_nontemporal_load(&kv_p[j * 64 + lane]);
    #pragma unroll
    for (int j = 0; j < 4; j++) VU[j] = __builtin_nontemporal_load(&vu_p[j * 64 + lane]);
    #pragma unroll
    for (int j = 0; j < 4; j++) VV[j] = __builtin_nontemporal_load(&vv_p[j * 64 + lane]);
    vf4 KE = __builtin_nontemporal_load(&((const vf4*)(ekw + eh * 256))[lane]);
    vf4 VE = __builtin_nontemporal_load(&((const vf4*)(evw + eh * 256))[lane]);
    vf4 FS = ((const vf4*)(feat + sn * EMBD))[c];     // reused: keep cached
    vf4 FD = ((const vf4*)(feat + dn * EMBD))[c];
    vf4 q4 = __builtin_nontemporal_load(&((const vf4*)(query + eh * 8))[half]);

    // ---------- small loads (biases: streamed; gamma/beta: cached) --------
    float kb1 = __builtin_nontemporal_load(skb + eh * 32 + f)
              + __builtin_nontemporal_load(dkb + eh * 32 + f);
    float vb1 = __builtin_nontemporal_load(svb + eh * 32 + f)
              + __builtin_nontemporal_load(dvb + eh * 32 + f);
    vf4 kb2 = __builtin_nontemporal_load(&((const vf4*)(ekb + eh * 8))[half]);
    vf4 vb2 = __builtin_nontemporal_load(&((const vf4*)(evb + eh * 8))[half]);
    vf4 kgam = ((const vf4*)kg)[half],   kbet = ((const vf4*)kbeta)[half];
    vf4 vgam = ((const vf4*)vg)[half],   vbet = ((const vf4*)vbeta)[half];

    // ---------- compute ----------------------------------------------------
    vf4 kn = ffn_compute(KU, KV, KE, FS, FD, kb1, kb2, kgam, kbet, lane);
    float lp = dot4v(kn, q4);
    lp += __shfl_xor(lp, 1);            // full logit on every lane

    vf4 vn = ffn_compute(VU, VV, VE, FS, FD, vb1, vb2, vgam, vbet, lane);

    float exv = expf(lp);               // no max-subtraction: identical softmax
    if (lane < 2) {                     // lanes 0/1 hold the 8 v components
        float* ap = agg + ((size_t)dn * NH + hh) * DHD + half * 4;
        atomicAdd(ap + 0, exv * vn.x);
        atomicAdd(ap + 1, exv * vn.y);
        atomicAdd(ap + 2, exv * vn.z);
        atomicAdd(ap + 3, exv * vn.w);
    }
    if (lane == 0) {
        ex_out[eh] = exv;
        atomicAdd(s_den + dn * NH + hh, exv);
    }
}

// Fused finalize: attn = ex/s per (edge,head); out = LN(agg/s) per (node,head).
__global__ void final_kernel(
    const int* __restrict__ dst, const float* __restrict__ ex,
    const float* __restrict__ s_den, const float* __restrict__ agg,
    const float* __restrict__ g, const float* __restrict__ b,
    float* __restrict__ out, float* __restrict__ attn_out)
{
    int tid = blockIdx.x * blockDim.x + threadIdx.x;
    if (tid < NE * NH) {
        int e = tid >> 2, h = tid & 3;
        attn_out[tid] = ex[tid] / s_den[dst[e] * NH + h];   // s>0: edge exists
    } else if (tid < NE * NH + NN * NH) {
        int t = tid - NE * NH;          // node-head index
        float s = s_den[t];
        float inv = (s > 0.0f) ? 1.0f / s : 0.0f;   // isolated node: agg==0
        vf4 a0 = *(const vf4*)(agg + t * 8)     * inv;
        vf4 a1 = *(const vf4*)(agg + t * 8 + 4) * inv;
        float s1 = a0.x + a0.y + a0.z + a0.w + a1.x + a1.y + a1.z + a1.w;
        float s2 = a0.x * a0.x + a0.y * a0.y + a0.z * a0.z + a0.w * a0.w
                 + a1.x * a1.x + a1.y * a1.y + a1.z * a1.z + a1.w * a1.w;
        float mean = s1 * 0.125f;
        float var  = s2 * 0.125f - mean * mean;
        float rs   = rsqrtf(var + EPSC);
        vf4 g0 = *(const vf4*)(g);
        vf4 g1 = *(const vf4*)(g + 4);
        vf4 b0 = *(const vf4*)(b);
        vf4 b1 = *(const vf4*)(b + 4);
        *(vf4*)(out + t * 8)     = (a0 - mean) * rs * g0 + b0;
        *(vf4*)(out + t * 8 + 4) = (a1 - mean) * rs * g1 + b1;
    }
}

extern "C" void kernel_launch(void* const* d_in, const int* in_sizes, int n_in,
                              void* d_out, int out_size, void* d_ws, size_t ws_size,
                              hipStream_t stream) {
    const float* feat  = (const float*)d_in[0];
    const float* query = (const float*)d_in[1];
    const float* skw   = (const float*)d_in[2];
    const float* dkw   = (const float*)d_in[3];
    const float* skb   = (const float*)d_in[4];
    const float* dkb   = (const float*)d_in[5];
    const float* ekw   = (const float*)d_in[6];
    const float* ekb   = (const float*)d_in[7];
    const float* svw   = (const float*)d_in[8];
    const float* dvw   = (const float*)d_in[9];
    const float* svb   = (const float*)d_in[10];
    const float* dvb   = (const float*)d_in[11];
    const float* evw   = (const float*)d_in[12];
    const float* evb   = (const float*)d_in[13];
    const float* kg    = (const float*)d_in[14];
    const float* kbeta = (const float*)d_in[15];
    const float* vg    = (const float*)d_in[16];
    const float* vbeta = (const float*)d_in[17];
    const float* og    = (const float*)d_in[18];
    const float* obeta = (const float*)d_in[19];
    const int*   src   = (const int*)d_in[20];
    const int*   dst   = (const int*)d_in[21];
    // d_in[22] = i, always 0 (L=1)

    float* ws    = (float*)d_ws;
    float* s_den = ws;                 // N*H    = 10000
    float* agg   = ws + 10000;         // N*H*DH = 80000 (unnormalized)
    float* ex    = ws + 90000;         // E*H    = 40000

    float* out  = (float*)d_out;       // N*EMB = 80000 floats; attn follows

    hipMemsetAsync(ws, 0, 90000 * sizeof(float), stream);

    edge_kernel<<<(NE * NH * 64) / 256, 256, 0, stream>>>(
        feat, query, skw, dkw, skb, dkb, ekw, ekb,
        svw, dvw, svb, dvb, evw, evb,
        kg, kbeta, vg, vbeta, src, dst,
        s_den, agg, ex);

    final_kernel<<<(NE * NH + NN * NH + 255) / 256, 256, 0, stream>>>(
        dst, ex, s_den, agg, og, obeta, out, out + NN * EMBD);
}